// Round 1
// baseline (501.476 us; speedup 1.0000x reference)
//
#include <hip/hip_runtime.h>

// Matrix-factorization forward:
//   pred[b] = sum_h (user_weight[u][h] + user_bias[u]) * (item_weight[i][h] + item_bias[i]) + bias[0]
// B = 1,048,576, H = 64.
//
// Layout: 16 lanes per row -> each 16-lane group reads one contiguous 256 B
// weight row as float4 (perfect coalescing). 4 rows per wave, 16 per block.

__global__ __launch_bounds__(256) void MF_73856257622285_kernel(
    const int*   __restrict__ user,
    const int*   __restrict__ item,
    const float* __restrict__ user_weight,
    const float* __restrict__ item_weight,
    const float* __restrict__ user_bias,
    const float* __restrict__ item_bias,
    const float* __restrict__ bias,
    float*       __restrict__ out,
    int batch)
{
    const int lane16 = threadIdx.x & 15;
    const int row    = (int)((blockIdx.x * blockDim.x + threadIdx.x) >> 4);
    if (row >= batch) return;

    const int u  = user[row];
    const int it = item[row];

    const float ub = user_bias[u];
    const float ib = item_bias[it];

    const float4 uw = ((const float4*)(user_weight + (size_t)u  * 64))[lane16];
    const float4 iw = ((const float4*)(item_weight + (size_t)it * 64))[lane16];

    float s = (uw.x + ub) * (iw.x + ib)
            + (uw.y + ub) * (iw.y + ib)
            + (uw.z + ub) * (iw.z + ib)
            + (uw.w + ub) * (iw.w + ib);

    // Reduce across the 16 lanes of this group (in-wave, no LDS).
    s += __shfl_xor(s, 8, 16);
    s += __shfl_xor(s, 4, 16);
    s += __shfl_xor(s, 2, 16);
    s += __shfl_xor(s, 1, 16);

    if (lane16 == 0) out[row] = s + bias[0];
}

extern "C" void kernel_launch(void* const* d_in, const int* in_sizes, int n_in,
                              void* d_out, int out_size, void* d_ws, size_t ws_size,
                              hipStream_t stream) {
    const int*   user        = (const int*)  d_in[0];
    const int*   item        = (const int*)  d_in[1];
    // d_in[2] = target (unused in forward)
    const float* user_weight = (const float*)d_in[3];
    const float* item_weight = (const float*)d_in[4];
    const float* user_bias   = (const float*)d_in[5];
    const float* item_bias   = (const float*)d_in[6];
    const float* bias        = (const float*)d_in[7];
    float*       out         = (float*)d_out;

    const int batch = in_sizes[0];

    const int threads = 256;
    const int rows_per_block = threads / 16;            // 16
    const int blocks = (batch + rows_per_block - 1) / rows_per_block;

    MF_73856257622285_kernel<<<blocks, threads, 0, stream>>>(
        user, item, user_weight, item_weight, user_bias, item_bias, bias,
        out, batch);
}